// Round 15
// baseline (195.624 us; speedup 1.0000x reference)
//
#include <hip/hip_runtime.h>
#include <hip/hip_bf16.h>

typedef short bf16x8 __attribute__((ext_vector_type(8)));
typedef float f32x4 __attribute__((ext_vector_type(4)));
typedef ushort ushort8_t __attribute__((ext_vector_type(8)));

__device__ __forceinline__ float bf2f(ushort u) {
    union { unsigned int i; float f; } c; c.i = ((unsigned int)u) << 16; return c.f;
}
__device__ __forceinline__ ushort f2bf(float f) {
    union { float f; unsigned int i; } c; c.f = f;
    unsigned int x = c.i;
    return (ushort)((x + 0x7fffu + ((x >> 16) & 1u)) >> 16);  // RNE
}

#define GLOAD_LDS16(g, l) __builtin_amdgcn_global_load_lds( \
    (const __attribute__((address_space(1))) unsigned int*)(g), \
    (__attribute__((address_space(3))) unsigned int*)(l), 16, 0, 0)

// -------- fused prep: cvt(x) + transpose(W_qkv) + transpose(W_out) --------
__device__ __forceinline__ void transpose_cvt_body(const float* __restrict__ in,
                                                   ushort* __restrict__ out,
                                                   int K, int N, int bx, int by,
                                                   int tid, float (*tile)[33]) {
    int n0 = bx * 32, k0 = by * 32;
    int tx = tid & 31, ty = tid >> 5;           // (32,8)
    #pragma unroll
    for (int i = 0; i < 32; i += 8)
        tile[ty + i][tx] = in[(size_t)(k0 + ty + i) * N + n0 + tx];
    __syncthreads();
    #pragma unroll
    for (int i = 0; i < 32; i += 8)
        out[(size_t)(n0 + ty + i) * K + k0 + tx] = f2bf(tile[tx][ty + i]);
}

__global__ __launch_bounds__(256) void k_prep(const float* __restrict__ x,
                                              ushort* __restrict__ xb,
                                              const float* __restrict__ Wq,
                                              ushort* __restrict__ wqkT,
                                              const float* __restrict__ Wo,
                                              ushort* __restrict__ woT) {
    __shared__ float tile[32][33];
    const int b = blockIdx.x, tid = threadIdx.x;
    if (b < 16384) {
        int i = b * 256 + tid;
        float4 v = ((const float4*)x)[i];
        ushort4 o;
        o.x = f2bf(v.x); o.y = f2bf(v.y); o.z = f2bf(v.z); o.w = f2bf(v.w);
        ((ushort4*)xb)[i] = o;
    } else if (b < 16384 + 3072) {
        int idx = b - 16384;                    // 96 x 32
        transpose_cvt_body(Wq, wqkT, 1024, 3072, idx % 96, idx / 96, tid, tile);
    } else {
        int idx = b - (16384 + 3072);           // 32 x 32
        transpose_cvt_body(Wo, woT, 1024, 1024, idx & 31, idx >> 5, tid, tile);
    }
}

// ========== GEMM1: 256x256 8-phase, ONE barrier per phase (K=1024) ========
// Best measured variant (r8/r11/r13): 8 waves (2Mx4N), wave tile 128x64,
// BK=64, LDS 128KB, conflict-free swizzle (SQ_LDS_BANK_CONFLICT == 0),
// phase = {reads; stage; MFMA; SB0; vm; BAR; SB0}, VM10 at ph2/4/6/8.
// Ten schedule/shape/occupancy variants (r2-r14) all land 105-118us at
// 41+-1% MfmaUtil -> shape-adjusted plateau for this structure at K=1024.

#define LDSA(c,kk) (lds + (c)*65536 + (kk)*16384)
#define LDSB(c,kk) (lds + (c)*65536 + 32768 + (kk)*16384)
#define STAGE_A(c,kk,col) do { \
    GLOAD_LDS16(gA0 + (col), LDSA(c,kk) + wave*1024); \
    GLOAD_LDS16(gA1 + (col), LDSA(c,kk) + 8192 + wave*1024); } while(0)
#define STAGE_B(c,kk,col) do { \
    GLOAD_LDS16(gB0 + (col), LDSB(c,kk) + wave*1024); \
    GLOAD_LDS16(gB1 + (col), LDSB(c,kk) + 8192 + wave*1024); } while(0)
#define READ_A8(c,kk) do { const char* _p = LDSA(c,kk) + aoff; \
    _Pragma("unroll") for (int m = 0; m < 8; ++m) af[m] = *(const bf16x8*)(_p + m*1024); } while(0)
#define READ_B2(c,kk,n0) do { const char* _p = LDSB(c,kk) + boff; \
    bfr[n0] = *(const bf16x8*)(_p + (n0)*1024); \
    bfr[(n0)+1] = *(const bf16x8*)(_p + ((n0)+1)*1024); } while(0)
#define MF16(n0) do { __builtin_amdgcn_s_setprio(1); \
    _Pragma("unroll") for (int m = 0; m < 8; ++m) { \
    acc[m][n0]     = __builtin_amdgcn_mfma_f32_16x16x32_bf16(af[m], bfr[n0],     acc[m][n0],     0,0,0); \
    acc[m][(n0)+1] = __builtin_amdgcn_mfma_f32_16x16x32_bf16(af[m], bfr[(n0)+1], acc[m][(n0)+1], 0,0,0); } \
    __builtin_amdgcn_s_setprio(0); } while(0)

#define BAR __builtin_amdgcn_s_barrier()
#define SB0 __builtin_amdgcn_sched_barrier(0)
#define VM10 asm volatile("s_waitcnt vmcnt(10)")
#define VM4  asm volatile("s_waitcnt vmcnt(4)")
#define VM0  asm volatile("s_waitcnt vmcnt(0)")

#define PH1(reads, stage, mf, vm) do { reads; stage; mf; SB0; vm; BAR; SB0; } while(0)

#define ITERX(kb, LAST) do { \
  /*1*/ PH1( { READ_A8(0,0); READ_B2(0,0,0); }, STAGE_B(1,1,(kb)+96),              MF16(0), ); \
  /*2*/ PH1( { READ_B2(0,0,2); },               if(!(LAST)) STAGE_A(0,0,(kb)+128), MF16(2), if(LAST) VM0; else VM10 ); \
  /*3*/ PH1( { READ_A8(0,1); READ_B2(0,1,0); }, if(!(LAST)) STAGE_B(0,0,(kb)+128), MF16(0), ); \
  /*4*/ PH1( { READ_B2(0,1,2); },               if(!(LAST)) STAGE_A(0,1,(kb)+160), MF16(2), if(!(LAST)) VM10 ); \
  /*5*/ PH1( { READ_A8(1,0); READ_B2(1,0,0); }, if(!(LAST)) STAGE_B(0,1,(kb)+160), MF16(0), ); \
  /*6*/ PH1( { READ_B2(1,0,2); },               if(!(LAST)) STAGE_A(1,0,(kb)+192), MF16(2), if(!(LAST)) VM10 ); \
  /*7*/ PH1( { READ_A8(1,1); READ_B2(1,1,0); }, if(!(LAST)) STAGE_B(1,0,(kb)+192), MF16(0), ); \
  /*8*/ PH1( { READ_B2(1,1,2); },               if(!(LAST)) STAGE_A(1,1,(kb)+224), MF16(2), if(!(LAST)) VM10 ); \
} while(0)

template<bool OUT_BF16>
__global__ __launch_bounds__(512, 2) void k_gemm256(const ushort* __restrict__ A,
                                                    const ushort* __restrict__ Bt,
                                                    const float* __restrict__ bias,
                                                    void* __restrict__ Cout,
                                                    int N, int NTN) {
    __shared__ __align__(16) char lds[131072];
    const int K = 1024;
    const int tid = threadIdx.x;
    const int wave = tid >> 6, lane = tid & 63;
    const int wr = wave >> 2, wc = wave & 3;
    const int r = lane & 15, q = lane >> 4;

    // bijective XCD swizzle (gridDim.x % 8 == 0)
    const int cpx = gridDim.x >> 3, wg = blockIdx.x;
    const int swz = (wg & 7) * cpx + (wg >> 3);
    const int tm = swz / NTN, tn = swz - tm * NTN;
    const int bm = tm * 256, bn = tn * 256;

    // staging lane pointers (source pre-swizzled: chunk ^= (row>>1)&3)
    const int srow = tid >> 2;                      // 0..127
    const int c16l = (tid & 3) ^ ((srow >> 1) & 3);
    const ushort* gA0 = A  + (size_t)(bm + srow) * K + c16l * 8;
    const ushort* gA1 = gA0 + (size_t)128 * K;
    const ushort* gB0 = Bt + (size_t)(bn + srow) * K + c16l * 8;
    const ushort* gB1 = gB0 + (size_t)128 * K;

    // swizzled ds_read offsets: chunk = q ^ ((row>>1)&3)
    const int chunkx = ((q ^ ((r >> 1) & 3)) << 4);
    const int aoff = (wr * 128 + r) * 64 + chunkx;
    const int boff = (wc * 64 + r) * 64 + chunkx;

    f32x4 acc[8][4];
    #pragma unroll
    for (int m = 0; m < 8; ++m)
        #pragma unroll
        for (int n = 0; n < 4; ++n)
            acc[m][n] = (f32x4){0.f, 0.f, 0.f, 0.f};
    bf16x8 af[8], bfr[4];

    STAGE_A(0,0,0);  STAGE_B(0,0,0);
    STAGE_A(0,1,32); STAGE_B(0,1,32);
    STAGE_A(1,0,64); STAGE_B(1,0,64);
    STAGE_A(1,1,96);
    VM10; BAR; SB0;

    #pragma unroll 1
    for (int i = 0; i < 7; ++i) { ITERX(i * 128, 0); }
    ITERX(896, 1);

    float* Cf = (float*)Cout;
    ushort* Cb = (ushort*)Cout;
    #pragma unroll
    for (int m = 0; m < 8; ++m) {
        int row0 = bm + wr * 128 + m * 16 + q * 4;
        #pragma unroll
        for (int n = 0; n < 4; ++n) {
            int col = bn + wc * 64 + n * 16 + r;
            float bv = bias[col];
            #pragma unroll
            for (int j = 0; j < 4; ++j) {
                float v = acc[m][n][j] + bv;
                if (OUT_BF16) Cb[(size_t)(row0 + j) * N + col] = f2bf(v);
                else          Cf[(size_t)(row0 + j) * N + col] = v;
            }
        }
    }
}

// ==== GEMM2: 128x128 tile, BK=32, 3-deep 48KB LDS -> 3 blocks/CU =========
// GEMM2's grid (256 blocks at 256-tile) = ONE round of CUs: fill/stall/
// epilogue un-overlapped.  128^2 tile -> 1024 blocks, 4 staggered rounds,
// 3 blocks/CU (48KB LDS, launch_bounds(256,3): 170-reg budget >= ~130 used
// -> no spill).  4 waves (2Mx2N), wave tile 64x64 (acc[4][4] = 64 VGPR).
// r14-proven single-barrier 3-buf rotation; VM4 stagger re-derived for
// 4-load stage units: prologue tiles 0,1 (8 loads) + VM4 retires tile 0;
// steady VM4 leaves only tile t+2's 4 loads -> t+1 RAW-certified; WAR: buf
// (t+2)%3 last read at t-1, >=1 barrier ahead.  Same conflict-free swizzle
// (regions [128][32], 64B rows, bases mod 16 -> (row>>1)&3 == (r>>1)&3).

#define LDS2A(c) (lds + (size_t)(c) * 16384)
#define LDS2B(c) (lds + (size_t)(c) * 16384 + 8192)
#define STAGE2_A(c,col) do { \
    GLOAD_LDS16(gA0 + (col), LDS2A(c) + wave*1024); \
    GLOAD_LDS16(gA1 + (col), LDS2A(c) + 4096 + wave*1024); } while(0)
#define STAGE2_B(c,col) do { \
    GLOAD_LDS16(gB0 + (col), LDS2B(c) + wave*1024); \
    GLOAD_LDS16(gB1 + (col), LDS2B(c) + 4096 + wave*1024); } while(0)

template<bool OUT_BF16>
__global__ __launch_bounds__(256, 3) void k_gemm128(const ushort* __restrict__ A,
                                                    const ushort* __restrict__ Bt,
                                                    const float* __restrict__ bias,
                                                    void* __restrict__ Cout,
                                                    int N, int NTN) {
    __shared__ __align__(16) char lds[49152];
    const int K = 1024, NT = 32;
    const int tid = threadIdx.x;
    const int wave = tid >> 6, lane = tid & 63;
    const int wr = wave >> 1, wc = wave & 1;
    const int r = lane & 15, q = lane >> 4;

    // bijective XCD swizzle (gridDim.x % 8 == 0)
    const int cpx = gridDim.x >> 3, wg = blockIdx.x;
    const int swz = (wg & 7) * cpx + (wg >> 3);
    const int tm = swz / NTN, tn = swz - tm * NTN;
    const int bm = tm * 128, bn = tn * 128;

    // staging: [128][32] region = 512 chunks; thread does rows srow, srow+64
    const int srow = tid >> 2;                      // 0..63
    const int c16l = (tid & 3) ^ ((srow >> 1) & 3);
    const ushort* gA0 = A  + (size_t)(bm + srow) * K + c16l * 8;
    const ushort* gA1 = gA0 + (size_t)64 * K;
    const ushort* gB0 = Bt + (size_t)(bn + srow) * K + c16l * 8;
    const ushort* gB1 = gB0 + (size_t)64 * K;

    const int chunkx = ((q ^ ((r >> 1) & 3)) << 4);
    const int aoff = (wr * 64 + r) * 64 + chunkx;
    const int boff = (wc * 64 + r) * 64 + chunkx;

    f32x4 acc[4][4];
    #pragma unroll
    for (int m = 0; m < 4; ++m)
        #pragma unroll
        for (int n = 0; n < 4; ++n)
            acc[m][n] = (f32x4){0.f, 0.f, 0.f, 0.f};
    bf16x8 af[4], bfr[4];

    // prologue: tiles 0,1 (8 loads); VM4 retires tile 0's 4.
    STAGE2_A(0, 0);  STAGE2_B(0, 0);
    STAGE2_A(1, 32); STAGE2_B(1, 32);
    VM4; BAR;

    int ca = 0;
    #pragma unroll 1
    for (int t = 0; t < NT; ++t) {
        const char* pA = LDS2A(ca) + aoff;
        const char* pB = LDS2B(ca) + boff;
        #pragma unroll
        for (int m = 0; m < 4; ++m) af[m] = *(const bf16x8*)(pA + m * 1024);
        #pragma unroll
        for (int n = 0; n < 4; ++n) bfr[n] = *(const bf16x8*)(pB + n * 1024);
        int cs = ca + 2; if (cs >= 3) cs -= 3;
        if (t < NT - 2) { STAGE2_A(cs, (t + 2) * 32); STAGE2_B(cs, (t + 2) * 32); }
        __builtin_amdgcn_s_setprio(1);
        #pragma unroll
        for (int m = 0; m < 4; ++m)
            #pragma unroll
            for (int n = 0; n < 4; ++n)
                acc[m][n] = __builtin_amdgcn_mfma_f32_16x16x32_bf16(af[m], bfr[n], acc[m][n], 0, 0, 0);
        __builtin_amdgcn_s_setprio(0);
        if (t < NT - 2) VM4; else if (t == NT - 2) VM0;
        BAR;
        ++ca; if (ca == 3) ca = 0;
    }

    float* Cf = (float*)Cout;
    ushort* Cb = (ushort*)Cout;
    #pragma unroll
    for (int m = 0; m < 4; ++m) {
        int row0 = bm + wr * 64 + m * 16 + q * 4;
        #pragma unroll
        for (int n = 0; n < 4; ++n) {
            int col = bn + wc * 64 + n * 16 + r;
            float bv = bias[col];
            #pragma unroll
            for (int j = 0; j < 4; ++j) {
                float v = acc[m][n][j] + bv;
                if (OUT_BF16) Cb[(size_t)(row0 + j) * N + col] = f2bf(v);
                else          Cf[(size_t)(row0 + j) * N + col] = v;
            }
        }
    }
}

// -------- per-token head-mixing attention, MFMA, 1 wave/token, LDS V ------
__global__ __launch_bounds__(256) void k_attn_mfma(const ushort* __restrict__ qkv,
                                                   ushort* __restrict__ ctx) {
    __shared__ __align__(16) ushort vlds[4][1024];   // per-wave V [16][64]
    __shared__ __align__(16) ushort olds[4][1024];   // per-wave ctx [16][64]
    const int w = threadIdx.x >> 6, lane = threadIdx.x & 63;
    const size_t tok = (size_t)blockIdx.x * 4 + w;
    const ushort* row = qkv + tok * 3072;
    const int r = lane & 15, g = lane >> 4;

    {
        const int c0 = lane, c1 = lane + 64;
        bf16x8 v0 = *(const bf16x8*)(row + (c0 >> 3) * 192 + 128 + (c0 & 7) * 8);
        bf16x8 v1 = *(const bf16x8*)(row + (c1 >> 3) * 192 + 128 + (c1 & 7) * 8);
        *(bf16x8*)&vlds[w][c0 * 8] = v0;
        *(bf16x8*)&vlds[w][c1 * 8] = v1;
    }

    bf16x8 ka[2], qb[2];
    #pragma unroll
    for (int c = 0; c < 2; ++c) {
        ka[c] = *(const bf16x8*)(row + r * 192 + 64 + c * 32 + g * 8);  // K[r][d]
        qb[c] = *(const bf16x8*)(row + r * 192 +      c * 32 + g * 8);  // Q[r][d]
    }
    f32x4 st = (f32x4){0.f, 0.f, 0.f, 0.f};
    st = __builtin_amdgcn_mfma_f32_16x16x32_bf16(ka[0], qb[0], st, 0, 0, 0);
    st = __builtin_amdgcn_mfma_f32_16x16x32_bf16(ka[1], qb[1], st, 0, 0, 0);

    float s[4];
    #pragma unroll
    for (int j = 0; j < 4; ++j) s[j] = st[j] * 0.125f;
    float m = fmaxf(fmaxf(s[0], s[1]), fmaxf(s[2], s[3]));
    m = fmaxf(m, __shfl_xor(m, 16));
    m = fmaxf(m, __shfl_xor(m, 32));
    float p[4], sum = 0.f;
    #pragma unroll
    for (int j = 0; j < 4; ++j) { p[j] = __expf(s[j] - m); sum += p[j]; }
    sum += __shfl_xor(sum, 16);
    sum += __shfl_xor(sum, 32);
    float inv = 1.f / sum;
    #pragma unroll
    for (int j = 0; j < 4; ++j) p[j] *= inv;

    const bool gok = (g < 2);
    const int src0 = (r + 32 * g) & 63, src1 = (src0 + 16) & 63;
    bf16x8 pa;
    #pragma unroll
    for (int j = 0; j < 4; ++j) {
        float a0 = __shfl(p[j], src0, 64);
        float a1 = __shfl(p[j], src1, 64);
        pa[j]     = (short)(gok ? f2bf(a0) : (ushort)0);
        pa[4 + j] = (short)(gok ? f2bf(a1) : (ushort)0);
    }

    #pragma unroll
    for (int db = 0; db < 4; ++db) {
        bf16x8 vb;
        #pragma unroll
        for (int j = 0; j < 8; ++j) {
            int vrow = (g & 1) * 8 + j;               // == g*8+j for g<2
            ushort ve = vlds[w][vrow * 64 + db * 16 + r];
            vb[j] = (short)(gok ? ve : (ushort)0);
        }
        f32x4 o = (f32x4){0.f, 0.f, 0.f, 0.f};
        o = __builtin_amdgcn_mfma_f32_16x16x32_bf16(pa, vb, o, 0, 0, 0);
        #pragma unroll
        for (int j = 0; j < 4; ++j)
            olds[w][(4 * g + j) * 64 + db * 16 + r] = f2bf(o[j]);
    }

    {
        const int c0 = lane, c1 = lane + 64;
        bf16x8 o0 = *(const bf16x8*)&olds[w][c0 * 8];
        bf16x8 o1 = *(const bf16x8*)&olds[w][c1 * 8];
        *(bf16x8*)(ctx + tok * 1024 + c0 * 8) = o0;
        *(bf16x8*)(ctx + tok * 1024 + c1 * 8) = o1;
    }
}

extern "C" void kernel_launch(void* const* d_in, const int* in_sizes, int n_in,
                              void* d_out, int out_size, void* d_ws, size_t ws_size,
                              hipStream_t stream) {
    const float* x     = (const float*)d_in[0];
    const float* W_qkv = (const float*)d_in[1];
    const float* b_qkv = (const float*)d_in[2];
    const float* W_out = (const float*)d_in[3];
    const float* b_out = (const float*)d_in[4];

    const int M = 16384, D = 1024, N3 = 3072;

    ushort* xb   = (ushort*)d_ws;
    ushort* wqkT = xb + (size_t)M * D;
    ushort* woT  = wqkT + (size_t)N3 * D;
    ushort* qkv  = woT + (size_t)D * D;
    ushort* ctx  = xb;  // xb dead after GEMM1; reuse for context

    hipLaunchKernelGGL(k_prep, dim3(16384 + 3072 + 1024), dim3(256), 0, stream,
                       x, xb, W_qkv, wqkT, W_out, woT);
    hipLaunchKernelGGL((k_gemm256<true>), dim3((N3 / 256) * (M / 256)), dim3(512), 0, stream,
                       xb, wqkT, b_qkv, (void*)qkv, N3, N3 / 256);
    hipLaunchKernelGGL(k_attn_mfma, dim3(M / 4), dim3(256), 0, stream, qkv, ctx);
    hipLaunchKernelGGL((k_gemm128<false>), dim3((D / 128) * (M / 128)), dim3(256), 0, stream,
                       ctx, woT, b_out, d_out, D, D / 128);
}

// Round 16
// 189.124 us; speedup vs baseline: 1.0344x; 1.0344x over previous
//
#include <hip/hip_runtime.h>
#include <hip/hip_bf16.h>

typedef short bf16x8 __attribute__((ext_vector_type(8)));
typedef float f32x4 __attribute__((ext_vector_type(4)));
typedef ushort ushort8_t __attribute__((ext_vector_type(8)));

__device__ __forceinline__ float bf2f(ushort u) {
    union { unsigned int i; float f; } c; c.i = ((unsigned int)u) << 16; return c.f;
}
__device__ __forceinline__ ushort f2bf(float f) {
    union { float f; unsigned int i; } c; c.f = f;
    unsigned int x = c.i;
    return (ushort)((x + 0x7fffu + ((x >> 16) & 1u)) >> 16);  // RNE
}

#define GLOAD_LDS16(g, l) __builtin_amdgcn_global_load_lds( \
    (const __attribute__((address_space(1))) unsigned int*)(g), \
    (__attribute__((address_space(3))) unsigned int*)(l), 16, 0, 0)

// -------- fused prep: cvt(x) + transpose(W_qkv) + transpose(W_out) --------
__device__ __forceinline__ void transpose_cvt_body(const float* __restrict__ in,
                                                   ushort* __restrict__ out,
                                                   int K, int N, int bx, int by,
                                                   int tid, float (*tile)[33]) {
    int n0 = bx * 32, k0 = by * 32;
    int tx = tid & 31, ty = tid >> 5;           // (32,8)
    #pragma unroll
    for (int i = 0; i < 32; i += 8)
        tile[ty + i][tx] = in[(size_t)(k0 + ty + i) * N + n0 + tx];
    __syncthreads();
    #pragma unroll
    for (int i = 0; i < 32; i += 8)
        out[(size_t)(n0 + ty + i) * K + k0 + tx] = f2bf(tile[tx][ty + i]);
}

__global__ __launch_bounds__(256) void k_prep(const float* __restrict__ x,
                                              ushort* __restrict__ xb,
                                              const float* __restrict__ Wq,
                                              ushort* __restrict__ wqkT,
                                              const float* __restrict__ Wo,
                                              ushort* __restrict__ woT) {
    __shared__ float tile[32][33];
    const int b = blockIdx.x, tid = threadIdx.x;
    if (b < 16384) {
        int i = b * 256 + tid;
        float4 v = ((const float4*)x)[i];
        ushort4 o;
        o.x = f2bf(v.x); o.y = f2bf(v.y); o.z = f2bf(v.z); o.w = f2bf(v.w);
        ((ushort4*)xb)[i] = o;
    } else if (b < 16384 + 3072) {
        int idx = b - 16384;                    // 96 x 32
        transpose_cvt_body(Wq, wqkT, 1024, 3072, idx % 96, idx / 96, tid, tile);
    } else {
        int idx = b - (16384 + 3072);           // 32 x 32
        transpose_cvt_body(Wo, woT, 1024, 1024, idx & 31, idx >> 5, tid, tile);
    }
}

// ========== 256x256 8-phase GEMM, ONE barrier per phase (K=1024) ==========
// Best measured variant (r8/r11/r13): 8 waves (2Mx4N), wave tile 128x64,
// BK=64, LDS 128KB, conflict-free swizzle (SQ_LDS_BANK_CONFLICT == 0),
// phase = {reads; stage; MFMA; SB0; vm; BAR; SB0}, VM10 at ph2/4/6/8.
// Ten schedule/shape/occupancy variants (r2-r15) all land 105-118us at
// 41+-1% MfmaUtil -> shape-adjusted plateau for this structure at K=1024.

#define LDSA(c,kk) (lds + (c)*65536 + (kk)*16384)
#define LDSB(c,kk) (lds + (c)*65536 + 32768 + (kk)*16384)
#define STAGE_A(c,kk,col) do { \
    GLOAD_LDS16(gA0 + (col), LDSA(c,kk) + wave*1024); \
    GLOAD_LDS16(gA1 + (col), LDSA(c,kk) + 8192 + wave*1024); } while(0)
#define STAGE_B(c,kk,col) do { \
    GLOAD_LDS16(gB0 + (col), LDSB(c,kk) + wave*1024); \
    GLOAD_LDS16(gB1 + (col), LDSB(c,kk) + 8192 + wave*1024); } while(0)
#define READ_A8(c,kk) do { const char* _p = LDSA(c,kk) + aoff; \
    _Pragma("unroll") for (int m = 0; m < 8; ++m) af[m] = *(const bf16x8*)(_p + m*1024); } while(0)
#define READ_B2(c,kk,n0) do { const char* _p = LDSB(c,kk) + boff; \
    bfr[n0] = *(const bf16x8*)(_p + (n0)*1024); \
    bfr[(n0)+1] = *(const bf16x8*)(_p + ((n0)+1)*1024); } while(0)
#define MF16(n0) do { __builtin_amdgcn_s_setprio(1); \
    _Pragma("unroll") for (int m = 0; m < 8; ++m) { \
    acc[m][n0]     = __builtin_amdgcn_mfma_f32_16x16x32_bf16(af[m], bfr[n0],     acc[m][n0],     0,0,0); \
    acc[m][(n0)+1] = __builtin_amdgcn_mfma_f32_16x16x32_bf16(af[m], bfr[(n0)+1], acc[m][(n0)+1], 0,0,0); } \
    __builtin_amdgcn_s_setprio(0); } while(0)

#define BAR __builtin_amdgcn_s_barrier()
#define SB0 __builtin_amdgcn_sched_barrier(0)
#define VM10 asm volatile("s_waitcnt vmcnt(10)")
#define VM0  asm volatile("s_waitcnt vmcnt(0)")

#define PH1(reads, stage, mf, vm) do { reads; stage; mf; SB0; vm; BAR; SB0; } while(0)

#define ITERX(kb, LAST) do { \
  /*1*/ PH1( { READ_A8(0,0); READ_B2(0,0,0); }, STAGE_B(1,1,(kb)+96),              MF16(0), ); \
  /*2*/ PH1( { READ_B2(0,0,2); },               if(!(LAST)) STAGE_A(0,0,(kb)+128), MF16(2), if(LAST) VM0; else VM10 ); \
  /*3*/ PH1( { READ_A8(0,1); READ_B2(0,1,0); }, if(!(LAST)) STAGE_B(0,0,(kb)+128), MF16(0), ); \
  /*4*/ PH1( { READ_B2(0,1,2); },               if(!(LAST)) STAGE_A(0,1,(kb)+160), MF16(2), if(!(LAST)) VM10 ); \
  /*5*/ PH1( { READ_A8(1,0); READ_B2(1,0,0); }, if(!(LAST)) STAGE_B(0,1,(kb)+160), MF16(0), ); \
  /*6*/ PH1( { READ_B2(1,0,2); },               if(!(LAST)) STAGE_A(1,0,(kb)+192), MF16(2), if(!(LAST)) VM10 ); \
  /*7*/ PH1( { READ_A8(1,1); READ_B2(1,1,0); }, if(!(LAST)) STAGE_B(1,0,(kb)+192), MF16(0), ); \
  /*8*/ PH1( { READ_B2(1,1,2); },               if(!(LAST)) STAGE_A(1,1,(kb)+224), MF16(2), if(!(LAST)) VM10 ); \
} while(0)

template<bool OUT_BF16>
__global__ __launch_bounds__(512, 2) void k_gemm256(const ushort* __restrict__ A,
                                                    const ushort* __restrict__ Bt,
                                                    const float* __restrict__ bias,
                                                    void* __restrict__ Cout,
                                                    int N, int NTN) {
    __shared__ __align__(16) char lds[131072];
    const int K = 1024;
    const int tid = threadIdx.x;
    const int wave = tid >> 6, lane = tid & 63;
    const int wr = wave >> 2, wc = wave & 3;
    const int r = lane & 15, q = lane >> 4;

    // bijective XCD swizzle (gridDim.x % 8 == 0)
    const int cpx = gridDim.x >> 3, wg = blockIdx.x;
    const int swz = (wg & 7) * cpx + (wg >> 3);
    const int tm = swz / NTN, tn = swz - tm * NTN;
    const int bm = tm * 256, bn = tn * 256;

    // staging lane pointers (source pre-swizzled: chunk ^= (row>>1)&3)
    const int srow = tid >> 2;                      // 0..127
    const int c16l = (tid & 3) ^ ((srow >> 1) & 3);
    const ushort* gA0 = A  + (size_t)(bm + srow) * K + c16l * 8;
    const ushort* gA1 = gA0 + (size_t)128 * K;
    const ushort* gB0 = Bt + (size_t)(bn + srow) * K + c16l * 8;
    const ushort* gB1 = gB0 + (size_t)128 * K;

    // swizzled ds_read offsets: chunk = q ^ ((row>>1)&3)
    const int chunkx = ((q ^ ((r >> 1) & 3)) << 4);
    const int aoff = (wr * 128 + r) * 64 + chunkx;
    const int boff = (wc * 64 + r) * 64 + chunkx;

    f32x4 acc[8][4];
    #pragma unroll
    for (int m = 0; m < 8; ++m)
        #pragma unroll
        for (int n = 0; n < 4; ++n)
            acc[m][n] = (f32x4){0.f, 0.f, 0.f, 0.f};
    bf16x8 af[8], bfr[4];

    // prologue: stage A00,B00,A01,B01,A10,B10,A11 (14 loads); VM10 retires
    // the first 4 (= A00,B00) needed by iter0 phase 1.
    STAGE_A(0,0,0);  STAGE_B(0,0,0);
    STAGE_A(0,1,32); STAGE_B(0,1,32);
    STAGE_A(1,0,64); STAGE_B(1,0,64);
    STAGE_A(1,1,96);
    VM10; BAR; SB0;

    #pragma unroll 1
    for (int i = 0; i < 7; ++i) { ITERX(i * 128, 0); }
    ITERX(896, 1);

    float* Cf = (float*)Cout;
    ushort* Cb = (ushort*)Cout;
    #pragma unroll
    for (int m = 0; m < 8; ++m) {
        int row0 = bm + wr * 128 + m * 16 + q * 4;
        #pragma unroll
        for (int n = 0; n < 4; ++n) {
            int col = bn + wc * 64 + n * 16 + r;
            float bv = bias[col];
            #pragma unroll
            for (int j = 0; j < 4; ++j) {
                float v = acc[m][n][j] + bv;
                if (OUT_BF16) Cb[(size_t)(row0 + j) * N + col] = f2bf(v);
                else          Cf[(size_t)(row0 + j) * N + col] = v;
            }
        }
    }
}

// -------- per-token head-mixing attention, MFMA, 1 wave/token, LDS V ------
// qkv row layout: col = h*192 + {0..63 q, 64..127 k, 128..191 v}
// Swapped QK^T: S^T = mfma16x16x32(A=K, B=Q): lane(r=l&15,g=l>>4) holds
// S[qh=r][kh=4g+j].  Softmax over kh: in-lane (4) + shfl_xor 16,32.
// PV: A-frag P gathered with 8 shuffles (K padded to 32, g>=2 zero);
// B-frag V via per-wave LDS (2 coalesced bf16x8 loads, ds_read_u16
// broadcast reads); output staged to LDS, stored as 2 coalesced bf16x8.
// All traffic within-wave: no barriers.
__global__ __launch_bounds__(256) void k_attn_mfma(const ushort* __restrict__ qkv,
                                                   ushort* __restrict__ ctx) {
    __shared__ __align__(16) ushort vlds[4][1024];   // per-wave V [16][64]
    __shared__ __align__(16) ushort olds[4][1024];   // per-wave ctx [16][64]
    const int w = threadIdx.x >> 6, lane = threadIdx.x & 63;
    const size_t tok = (size_t)blockIdx.x * 4 + w;
    const ushort* row = qkv + tok * 3072;
    const int r = lane & 15, g = lane >> 4;

    // stage V: 128 8-el chunks; lane handles c=lane and c=lane+64
    {
        const int c0 = lane, c1 = lane + 64;
        bf16x8 v0 = *(const bf16x8*)(row + (c0 >> 3) * 192 + 128 + (c0 & 7) * 8);
        bf16x8 v1 = *(const bf16x8*)(row + (c1 >> 3) * 192 + 128 + (c1 & 7) * 8);
        *(bf16x8*)&vlds[w][c0 * 8] = v0;
        *(bf16x8*)&vlds[w][c1 * 8] = v1;
    }

    bf16x8 ka[2], qb[2];
    #pragma unroll
    for (int c = 0; c < 2; ++c) {
        ka[c] = *(const bf16x8*)(row + r * 192 + 64 + c * 32 + g * 8);  // K[r][d]
        qb[c] = *(const bf16x8*)(row + r * 192 +      c * 32 + g * 8);  // Q[r][d]
    }
    f32x4 st = (f32x4){0.f, 0.f, 0.f, 0.f};
    st = __builtin_amdgcn_mfma_f32_16x16x32_bf16(ka[0], qb[0], st, 0, 0, 0);
    st = __builtin_amdgcn_mfma_f32_16x16x32_bf16(ka[1], qb[1], st, 0, 0, 0);

    float s[4];
    #pragma unroll
    for (int j = 0; j < 4; ++j) s[j] = st[j] * 0.125f;
    float m = fmaxf(fmaxf(s[0], s[1]), fmaxf(s[2], s[3]));
    m = fmaxf(m, __shfl_xor(m, 16));
    m = fmaxf(m, __shfl_xor(m, 32));
    float p[4], sum = 0.f;
    #pragma unroll
    for (int j = 0; j < 4; ++j) { p[j] = __expf(s[j] - m); sum += p[j]; }
    sum += __shfl_xor(sum, 16);
    sum += __shfl_xor(sum, 32);
    float inv = 1.f / sum;
    #pragma unroll
    for (int j = 0; j < 4; ++j) p[j] *= inv;

    // gather A-frag: lane needs P[r][8g+j]; source lane r+32g (j0-3), +16 (j4-7)
    const bool gok = (g < 2);
    const int src0 = (r + 32 * g) & 63, src1 = (src0 + 16) & 63;
    bf16x8 pa;
    #pragma unroll
    for (int j = 0; j < 4; ++j) {
        float a0 = __shfl(p[j], src0, 64);
        float a1 = __shfl(p[j], src1, 64);
        pa[j]     = (short)(gok ? f2bf(a0) : (ushort)0);
        pa[4 + j] = (short)(gok ? f2bf(a1) : (ushort)0);
    }

    #pragma unroll
    for (int db = 0; db < 4; ++db) {
        bf16x8 vb;
        #pragma unroll
        for (int j = 0; j < 8; ++j) {
            int vrow = (g & 1) * 8 + j;               // == g*8+j for g<2
            ushort ve = vlds[w][vrow * 64 + db * 16 + r];
            vb[j] = (short)(gok ? ve : (ushort)0);
        }
        f32x4 o = (f32x4){0.f, 0.f, 0.f, 0.f};
        o = __builtin_amdgcn_mfma_f32_16x16x32_bf16(pa, vb, o, 0, 0, 0);
        #pragma unroll
        for (int j = 0; j < 4; ++j)
            olds[w][(4 * g + j) * 64 + db * 16 + r] = f2bf(o[j]);
    }

    // coalesced ctx store
    {
        const int c0 = lane, c1 = lane + 64;
        bf16x8 o0 = *(const bf16x8*)&olds[w][c0 * 8];
        bf16x8 o1 = *(const bf16x8*)&olds[w][c1 * 8];
        *(bf16x8*)(ctx + tok * 1024 + c0 * 8) = o0;
        *(bf16x8*)(ctx + tok * 1024 + c1 * 8) = o1;
    }
}

extern "C" void kernel_launch(void* const* d_in, const int* in_sizes, int n_in,
                              void* d_out, int out_size, void* d_ws, size_t ws_size,
                              hipStream_t stream) {
    const float* x     = (const float*)d_in[0];
    const float* W_qkv = (const float*)d_in[1];
    const float* b_qkv = (const float*)d_in[2];
    const float* W_out = (const float*)d_in[3];
    const float* b_out = (const float*)d_in[4];

    const int M = 16384, D = 1024, N3 = 3072;

    ushort* xb   = (ushort*)d_ws;
    ushort* wqkT = xb + (size_t)M * D;
    ushort* woT  = wqkT + (size_t)N3 * D;
    ushort* qkv  = woT + (size_t)D * D;
    ushort* ctx  = xb;  // xb dead after GEMM1; reuse for context

    hipLaunchKernelGGL(k_prep, dim3(16384 + 3072 + 1024), dim3(256), 0, stream,
                       x, xb, W_qkv, wqkT, W_out, woT);
    hipLaunchKernelGGL((k_gemm256<true>), dim3((N3 / 256) * (M / 256)), dim3(512), 0, stream,
                       xb, wqkT, b_qkv, (void*)qkv, N3, N3 / 256);
    hipLaunchKernelGGL(k_attn_mfma, dim3(M / 4), dim3(256), 0, stream, qkv, ctx);
    hipLaunchKernelGGL((k_gemm256<false>), dim3((D / 256) * (M / 256)), dim3(512), 0, stream,
                       ctx, woT, b_out, d_out, D, D / 256);
}